// Round 9
// baseline (709.279 us; speedup 1.0000x reference)
//
#include <hip/hip_runtime.h>
#include <hip/hip_bf16.h>

// Autoregressive LSTM: B=16384, T=60, D=34, E=128, H=64, n_seeds=10
// R9: wave-autonomous (R8 structure) with engineered register budget.
// 256 blocks x 256 thr (1/CU), each wave owns 16 batch rows, NO barriers in
// the time loops. Weights in LDS (Wg 102KB, Wp 18KB); biases in LDS tables;
// seed-enc weights (64 VGPRs) live only in a split-off seed loop; seed x
// loaded global->regs directly. Persistent AR regs ~100, peak ~190.

typedef float f32x4 __attribute__((ext_vector_type(4)));
typedef __bf16 bf16x8 __attribute__((ext_vector_type(8)));
typedef unsigned short u16x8 __attribute__((ext_vector_type(8)));
typedef unsigned short u16x4 __attribute__((ext_vector_type(4)));

#define MFMA_BF16(A, B, C) \
    __builtin_amdgcn_mfma_f32_16x16x32_bf16(__builtin_bit_cast(bf16x8, (A)), \
                                            __builtin_bit_cast(bf16x8, (B)), (C), 0, 0, 0)

__device__ __forceinline__ unsigned short f2b(float f) {
    return __builtin_bit_cast(unsigned short, (__bf16)f);
}
__device__ __forceinline__ unsigned pack2(float a, float b) {
    return (unsigned)f2b(a) | ((unsigned)f2b(b) << 16);
}
__device__ __forceinline__ float exp2_(float x) {
#if __has_builtin(__builtin_amdgcn_exp2f)
    return __builtin_amdgcn_exp2f(x);
#else
    return __exp2f(x);
#endif
}
__device__ __forceinline__ float rcp_(float x) { return __builtin_amdgcn_rcpf(x); }
__device__ __forceinline__ float sig_(float x) {
    return rcp_(1.0f + exp2_(-1.44269504f * x));
}
__device__ __forceinline__ float tanh_(float x) {
    return __builtin_fmaf(2.0f, rcp_(1.0f + exp2_(-2.88539008f * x)), -1.0f);
}

__global__ __launch_bounds__(256, 1) void ar_lstm_kernel(
    const float* __restrict__ x,      // (16384,60,34)
    const float* __restrict__ W_enc,  // (128,34)
    const float* __restrict__ b_enc,  // (128)
    const float* __restrict__ W_ih,   // (256,128)
    const float* __restrict__ W_hh,   // (256,64)
    const float* __restrict__ b_ih,   // (256)
    const float* __restrict__ b_hh,   // (256)
    const float* __restrict__ W_dec,  // (34,64)
    const float* __restrict__ b_dec,  // (34)
    float* __restrict__ out)          // (16384,50,34)
{
    // Row strides 400B/144B/272B/144B: dword-strides ≡ 4 mod 32 -> ~uniform banks.
    __shared__ __attribute__((aligned(16))) unsigned short Wg[256][200];    // [n][k: x0-127,h128-191,pad]
    __shared__ __attribute__((aligned(16))) unsigned short Wp[128][72];     // W' = W_enc@W_dec
    __shared__ __attribute__((aligned(16))) unsigned short xtr[4][16][136]; // per-wave rnn_in
    __shared__ __attribute__((aligned(16))) unsigned short htr[4][16][72];  // per-wave h
    __shared__ float bias_g_tab[256];
    __shared__ float bias_f_tab[128];

    const int tid = threadIdx.x;
    const int wv = tid >> 6;
    const int l  = tid & 63;
    const int lr = l & 15;
    const int lg = l >> 4;
    const int rowbase = blockIdx.x * 64 + wv * 16;

    // ===================== init (2 barriers total) =====================
    float* wdec_s = (float*)&xtr[0][0][0];   // 8704B f32 scratch inside xtr
    for (int i = tid; i < 34 * 64; i += 256) wdec_s[i] = W_dec[i];
    {
        const int n = tid;
        const float* wi = &W_ih[n * 128];
        for (int k = 0; k < 128; k += 2) *(unsigned*)&Wg[n][k] = pack2(wi[k], wi[k + 1]);
        const float* wh = &W_hh[n * 64];
        for (int k = 0; k < 64; k += 2) *(unsigned*)&Wg[n][128 + k] = pack2(wh[k], wh[k + 1]);
        for (int k = 192; k < 200; k += 2) *(unsigned*)&Wg[n][k] = 0;
        bias_g_tab[n] = b_ih[n] + b_hh[n];
    }
    __syncthreads();
    if (tid < 128) {
        const int n = tid;
        const float* we_row = &W_enc[n * 34];
        float bs = b_enc[n];
        for (int j = 0; j < 34; ++j) bs += we_row[j] * b_dec[j];
        bias_f_tab[n] = bs;
        for (int k = 0; k < 64; k += 2) {
            float s0 = 0.0f, s1 = 0.0f;
            for (int j = 0; j < 34; ++j) {
                float w = we_row[j];
                s0 += w * wdec_s[j * 64 + k];
                s1 += w * wdec_s[j * 64 + k + 1];
            }
            *(unsigned*)&Wp[n][k] = pack2(s0, s1);
        }
    }
    __syncthreads();   // Wp/tables done; xtr scratch free. No barriers after this.

    // ---- persistent registers (AR loop ~100 VGPRs) ----
    u16x8 wd[3][2];
    float bias_d[3];
    #pragma unroll
    for (int nt = 0; nt < 3; ++nt) {
        int n = nt * 16 + lr;
        bool v = n < 34;
        bias_d[nt] = v ? b_dec[n] : 0.0f;
        #pragma unroll
        for (int kt = 0; kt < 2; ++kt)
            #pragma unroll
            for (int i = 0; i < 8; ++i)
                wd[nt][kt][i] = v ? f2b(W_dec[n * 64 + kt * 32 + lg * 8 + i]) : (unsigned short)0;
    }
    u16x8 ax[4], ahh[2];
    #pragma unroll
    for (int kt = 0; kt < 4; ++kt)
        #pragma unroll
        for (int i = 0; i < 8; ++i) ax[kt][i] = 0;
    #pragma unroll
    for (int kt = 0; kt < 2; ++kt)
        #pragma unroll
        for (int i = 0; i < 8; ++i) ahh[kt][i] = 0;
    float c_st[4][4];
    #pragma unroll
    for (int a = 0; a < 4; ++a)
        #pragma unroll
        for (int r = 0; r < 4; ++r) c_st[a][r] = 0.0f;

    // gates + cell (reads ax/ahh, updates c_st, refreshes ahh via htr)
    auto GATES = [&]() {
        #pragma unroll
        for (int jt = 0; jt < 4; ++jt) {
            f32x4 acc0 = *(const f32x4*)&bias_g_tab[(0 * 4 + jt) * 16 + lg * 4];
            f32x4 acc1 = *(const f32x4*)&bias_g_tab[(1 * 4 + jt) * 16 + lg * 4];
            f32x4 acc2 = *(const f32x4*)&bias_g_tab[(2 * 4 + jt) * 16 + lg * 4];
            f32x4 acc3 = *(const f32x4*)&bias_g_tab[(3 * 4 + jt) * 16 + lg * 4];
            #pragma unroll
            for (int kt = 0; kt < 6; ++kt) {
                u16x8 bfr = (kt < 4) ? ax[kt] : ahh[kt - 4];
                const int co = kt * 32 + lg * 8;
                acc0 = MFMA_BF16(*(const u16x8*)&Wg[(0 * 4 + jt) * 16 + lr][co], bfr, acc0);
                acc1 = MFMA_BF16(*(const u16x8*)&Wg[(1 * 4 + jt) * 16 + lr][co], bfr, acc1);
                acc2 = MFMA_BF16(*(const u16x8*)&Wg[(2 * 4 + jt) * 16 + lr][co], bfr, acc2);
                acc3 = MFMA_BF16(*(const u16x8*)&Wg[(3 * 4 + jt) * 16 + lr][co], bfr, acc3);
            }
            u16x4 hv;
            #pragma unroll
            for (int r = 0; r < 4; ++r) {
                float cn = sig_(acc1[r]) * c_st[jt][r] + sig_(acc0[r]) * tanh_(acc2[r]);
                float hn = sig_(acc3[r]) * tanh_(cn);
                c_st[jt][r] = cn;
                hv[r] = f2b(hn);
            }
            *(u16x4*)&htr[wv][lr][jt * 16 + lg * 4] = hv;
        }
        ahh[0] = *(const u16x8*)&htr[wv][lr][lg * 8];
        ahh[1] = *(const u16x8*)&htr[wv][lr][32 + lg * 8];
    };
    // enc': rnn_in = relu(W' h + b') -> xtr -> ax
    auto ENCP = [&]() {
        #pragma unroll
        for (int ntl = 0; ntl < 8; ++ntl) {
            f32x4 a = *(const f32x4*)&bias_f_tab[ntl * 16 + lg * 4];
            a = MFMA_BF16(*(const u16x8*)&Wp[ntl * 16 + lr][lg * 8],      ahh[0], a);
            a = MFMA_BF16(*(const u16x8*)&Wp[ntl * 16 + lr][32 + lg * 8], ahh[1], a);
            u16x4 pv;
            #pragma unroll
            for (int r = 0; r < 4; ++r) pv[r] = f2b(fmaxf(a[r], 0.0f));
            *(u16x4*)&xtr[wv][lr][ntl * 16 + lg * 4] = pv;
        }
        #pragma unroll
        for (int kt = 0; kt < 4; ++kt)
            ax[kt] = *(const u16x8*)&xtr[wv][lr][kt * 32 + lg * 8];
    };

    // ===================== seed loop (t = 0..9) =====================
    {
        // seed-enc weight A-frags: live only in this scope (freed for AR loop)
        u16x8 wet[8][2];
        #pragma unroll
        for (int ntl = 0; ntl < 8; ++ntl) {
            int n = ntl * 16 + lr;
            #pragma unroll
            for (int kt = 0; kt < 2; ++kt)
                #pragma unroll
                for (int i = 0; i < 8; ++i) {
                    int k = kt * 32 + lg * 8 + i;
                    wet[ntl][kt][i] = (k < 34) ? f2b(W_enc[n * 34 + k]) : (unsigned short)0;
                }
        }
        for (int t = 0; t < 10; ++t) {
            const float* xf = &x[(size_t)(rowbase + lr) * 2040 + t * 34];
            u16x8 bd0, bd1;
            #pragma unroll
            for (int i = 0; i < 8; ++i) bd0[i] = f2b(xf[lg * 8 + i]);   // k<=31<34 ok
            #pragma unroll
            for (int i = 0; i < 8; ++i) bd1[i] = 0;
            if (lg == 0) { bd1[0] = f2b(xf[32]); bd1[1] = f2b(xf[33]); }
            #pragma unroll
            for (int ntl = 0; ntl < 8; ++ntl) {
                f32x4 a = *(const f32x4*)&b_enc[ntl * 16 + lg * 4];  // L1-resident
                a = MFMA_BF16(wet[ntl][0], bd0, a);
                a = MFMA_BF16(wet[ntl][1], bd1, a);
                u16x4 pv;
                #pragma unroll
                for (int r = 0; r < 4; ++r) pv[r] = f2b(fmaxf(a[r], 0.0f));
                *(u16x4*)&xtr[wv][lr][ntl * 16 + lg * 4] = pv;
            }
            #pragma unroll
            for (int kt = 0; kt < 4; ++kt)
                ax[kt] = *(const u16x8*)&xtr[wv][lr][kt * 32 + lg * 8];
            GATES();
        }
    }

    // ---- transition: prev = x[:,9,:]; rnn_in for t=10 ----
    float prev[3][4];
    #pragma unroll
    for (int nt = 0; nt < 3; ++nt) {
        int cidx = nt * 16 + lr;
        #pragma unroll
        for (int r = 0; r < 4; ++r)
            prev[nt][r] = (cidx < 34)
                ? x[(size_t)(rowbase + lg * 4 + r) * 2040 + 9 * 34 + cidx] : 0.0f;
    }
    ENCP();
    float* orow[4];
    #pragma unroll
    for (int r = 0; r < 4; ++r)
        orow[r] = out + (size_t)(rowbase + lg * 4 + r) * 1700;

    // ===================== AR loop (t = 10..59) =====================
    int toff = 0;
    for (int t = 10; t < 60; ++t) {
        GATES();
        #pragma unroll
        for (int nt = 0; nt < 3; ++nt) {
            f32x4 a = { bias_d[nt], bias_d[nt], bias_d[nt], bias_d[nt] };
            a = MFMA_BF16(ahh[0], wd[nt][0], a);
            a = MFMA_BF16(ahh[1], wd[nt][1], a);
            int cidx = nt * 16 + lr;
            if (cidx < 34)
                #pragma unroll
                for (int r = 0; r < 4; ++r) {
                    float o = a[r] + prev[nt][r];
                    prev[nt][r] = o;
                    orow[r][toff + cidx] = o;
                }
        }
        toff += 34;
        if (t < 59) ENCP();
    }
}

extern "C" void kernel_launch(void* const* d_in, const int* in_sizes, int n_in,
                              void* d_out, int out_size, void* d_ws, size_t ws_size,
                              hipStream_t stream) {
    const float* x     = (const float*)d_in[0];
    const float* W_enc = (const float*)d_in[1];
    const float* b_enc = (const float*)d_in[2];
    const float* W_ih  = (const float*)d_in[3];
    const float* W_hh  = (const float*)d_in[4];
    const float* b_ih  = (const float*)d_in[5];
    const float* b_hh  = (const float*)d_in[6];
    const float* W_dec = (const float*)d_in[7];
    const float* b_dec = (const float*)d_in[8];
    float* out = (float*)d_out;
    // n_seeds (d_in[9]) is compile-time 10 for this problem shape.
    ar_lstm_kernel<<<256, 256, 0, stream>>>(x, W_enc, b_enc, W_ih, W_hh,
                                            b_ih, b_hh, W_dec, b_dec, out);
}

// Round 10
// 187.031 us; speedup vs baseline: 3.7923x; 3.7923x over previous
//
#include <hip/hip_runtime.h>
#include <hip/hip_bf16.h>

// Autoregressive LSTM: B=16384, T=60, D=34, E=128, H=64, n_seeds=10
// Persistent block = 32 batch rows x 60 steps, 4 waves, 512 blocks (2/CU).
// R10 = R3 anchor (213us rocprof, zero spill) + ONE change: in-loop barriers
// are `s_waitcnt lgkmcnt(0); s_barrier` instead of __syncthreads(), skipping
// the vmcnt(0) drain of global out-stores / seed prefetch loads that no LDS
// consumer needs. All cross-wave deps in the loop are LDS (lgkmcnt-counted).

typedef float f32x4 __attribute__((ext_vector_type(4)));
typedef __bf16 bf16x8 __attribute__((ext_vector_type(8)));
typedef unsigned short u16x8 __attribute__((ext_vector_type(8)));

#define MFMA_BF16(A, B, C) \
    __builtin_amdgcn_mfma_f32_16x16x32_bf16(__builtin_bit_cast(bf16x8, (A)), \
                                            __builtin_bit_cast(bf16x8, (B)), (C), 0, 0, 0)

// LDS-only barrier: order ds ops across waves without draining global stores.
#define BARRIER_LDS() asm volatile("s_waitcnt lgkmcnt(0)\n\ts_barrier" ::: "memory")

__device__ __forceinline__ unsigned short f2b(float f) {
    return __builtin_bit_cast(unsigned short, (__bf16)f);
}
__device__ __forceinline__ float exp2_(float x) {
#if __has_builtin(__builtin_amdgcn_exp2f)
    return __builtin_amdgcn_exp2f(x);
#else
    return __exp2f(x);
#endif
}
__device__ __forceinline__ float rcp_(float x) {
    return __builtin_amdgcn_rcpf(x);
}
__device__ __forceinline__ float sig_(float x) {
    return rcp_(1.0f + exp2_(-1.44269504f * x));
}
__device__ __forceinline__ float tanh_(float x) {
    return __builtin_fmaf(2.0f, rcp_(1.0f + exp2_(-2.88539008f * x)), -1.0f);
}

__global__ __launch_bounds__(256, 2) void ar_lstm_kernel(
    const float* __restrict__ x,      // (16384,60,34)
    const float* __restrict__ W_enc,  // (128,34)
    const float* __restrict__ b_enc,  // (128)
    const float* __restrict__ W_ih,   // (256,128)
    const float* __restrict__ W_hh,   // (256,64)
    const float* __restrict__ b_ih,   // (256)
    const float* __restrict__ b_hh,   // (256)
    const float* __restrict__ W_dec,  // (34,64)
    const float* __restrict__ b_dec,  // (34)
    float* __restrict__ out)          // (16384,50,34)
{
    // +8 u16 row pad => 16B bank rotation; 2-way conflicts only (free).
    __shared__ __attribute__((aligned(16))) unsigned short x_s[32][136];    // rnn_in (M x 128)
    __shared__ __attribute__((aligned(16))) unsigned short h_s[2][32][72];  // h double-buffered
    __shared__ __attribute__((aligned(16))) unsigned short d_s[2][32][72];  // seed input staging
    __shared__ __attribute__((aligned(16))) float wdec_f[34][64];           // W_dec fp32 (init only)
    __shared__ float bdec_f[34];

    const int tid = threadIdx.x;
    const int w  = tid >> 6;   // wave 0..3
    const int l  = tid & 63;
    const int lr = l & 15;     // A-row / B-col / D-col lane index
    const int lg = l >> 4;     // lane group 0..3
    const int b0 = blockIdx.x * 32;

    for (int i = tid; i < 32 * 136;    i += 256) (&x_s[0][0])[i] = 0;
    for (int i = tid; i < 2 * 32 * 72; i += 256) (&h_s[0][0][0])[i] = 0;
    for (int i = tid; i < 2 * 32 * 72; i += 256) (&d_s[0][0][0])[i] = 0;
    for (int i = tid; i < 34 * 64;     i += 256) (&wdec_f[0][0])[i] = W_dec[i];
    if (tid < 34) bdec_f[tid] = b_dec[tid];
    // stage seed frame t=0
    for (int e = tid; e < 32 * 34; e += 256) {
        int r = e / 34, d = e - r * 34;
        d_s[0][r][d] = f2b(x[((b0 + r) * 60 + 0) * 34 + d]);
    }

    // ---- weight fragments in registers ----
    // gates: wave w owns hidden cols j = w*16+lr for all 4 gates (n-tiles w+4g)
    u16x8 wg[4][6];
    float bias_g[4];
    for (int g = 0; g < 4; ++g) {
        int n = (w + 4 * g) * 16 + lr;
        bias_g[g] = b_ih[n] + b_hh[n];
        for (int kt = 0; kt < 4; ++kt)
            for (int i = 0; i < 8; ++i)
                wg[g][kt][i] = f2b(W_ih[n * 128 + kt * 32 + lg * 8 + i]);
        for (int kt = 0; kt < 2; ++kt)
            for (int i = 0; i < 8; ++i)
                wg[g][4 + kt][i] = f2b(W_hh[n * 64 + kt * 32 + lg * 8 + i]);
    }
    // seed encoder (K=34 zero-padded to 64)
    u16x8 we[2][2];
    float bias_e[2];
    for (int ntl = 0; ntl < 2; ++ntl) {
        int n = (w * 2 + ntl) * 16 + lr;
        bias_e[ntl] = b_enc[n];
        for (int kt = 0; kt < 2; ++kt)
            for (int i = 0; i < 8; ++i) {
                int k = kt * 32 + lg * 8 + i;
                we[ntl][kt][i] = (k < 34) ? f2b(W_enc[n * 34 + k]) : (unsigned short)0;
            }
    }
    // decoder (cols >= 34 zero; wave 3 never used)
    u16x8 wd[2];
    float bias_d = 0.0f;
    {
        int n = w * 16 + lr;
        bool v = (w < 3) && (n < 34);
        bias_d = v ? b_dec[n] : 0.0f;
        for (int kt = 0; kt < 2; ++kt)
            for (int i = 0; i < 8; ++i)
                wd[kt][i] = v ? f2b(W_dec[n * 64 + kt * 32 + lg * 8 + i]) : (unsigned short)0;
    }

    __syncthreads();  // init: full barrier (global loads feeding LDS)

    // ---- fused W' = W_enc @ W_dec (128x64), b' = b_enc + W_enc @ b_dec ----
    u16x8 wf[2][2];
    float bias_f[2];
    for (int ntl = 0; ntl < 2; ++ntl) {
        int n = (w * 2 + ntl) * 16 + lr;
        f32x4 av0 = {0,0,0,0}, av1 = {0,0,0,0}, av2 = {0,0,0,0}, av3 = {0,0,0,0};
        float bacc = b_enc[n];
        for (int j = 0; j < 34; ++j) {
            float wej = W_enc[n * 34 + j];
            bacc += wej * bdec_f[j];
            av0 += wej * *(const f32x4*)&wdec_f[j][lg * 8];
            av1 += wej * *(const f32x4*)&wdec_f[j][lg * 8 + 4];
            av2 += wej * *(const f32x4*)&wdec_f[j][32 + lg * 8];
            av3 += wej * *(const f32x4*)&wdec_f[j][32 + lg * 8 + 4];
        }
        bias_f[ntl] = bacc;
        for (int i = 0; i < 4; ++i) {
            wf[ntl][0][i]     = f2b(av0[i]);
            wf[ntl][0][4 + i] = f2b(av1[i]);
            wf[ntl][1][i]     = f2b(av2[i]);
            wf[ntl][1][4 + i] = f2b(av3[i]);
        }
    }

    float c_st[2][4], prev[2][4];
    for (int mt = 0; mt < 2; ++mt)
        for (int r = 0; r < 4; ++r) { c_st[mt][r] = 0.0f; prev[mt][r] = 0.0f; }

    for (int t = 0; t < 60; ++t) {
        const int hw = t & 1;       // cell writes h_s[hw]
        const int hr = hw ^ 1;      // gates read h_s[hr]

        if (t < 10) {
            // seed encode: x_s = relu(d_s[hw] @ we^T); prefetch next seed frame
            u16x8 ad[2][2];
            for (int mt = 0; mt < 2; ++mt)
                for (int kt = 0; kt < 2; ++kt)
                    ad[mt][kt] = *(const u16x8*)&d_s[hw][mt * 16 + lr][kt * 32 + lg * 8];
            for (int mt = 0; mt < 2; ++mt)
                for (int ntl = 0; ntl < 2; ++ntl) {
                    f32x4 a = {bias_e[ntl], bias_e[ntl], bias_e[ntl], bias_e[ntl]};
                    a = MFMA_BF16(ad[mt][0], we[ntl][0], a);
                    a = MFMA_BF16(ad[mt][1], we[ntl][1], a);
                    for (int r = 0; r < 4; ++r)
                        x_s[mt * 16 + lg * 4 + r][(w * 2 + ntl) * 16 + lr] = f2b(fmaxf(a[r], 0.0f));
                }
            if (t + 1 < 10)
                for (int e = tid; e < 32 * 34; e += 256) {
                    int r = e / 34, d = e - r * 34;
                    d_s[hr][r][d] = f2b(x[((b0 + r) * 60 + (t + 1)) * 34 + d]);
                }
            BARRIER_LDS();
        }

        // ---- gates GEMM + cell, one 16-row tile at a time ----
        for (int mt = 0; mt < 2; ++mt) {
            u16x8 ax[4], ah[2];
            for (int kt = 0; kt < 4; ++kt)
                ax[kt] = *(const u16x8*)&x_s[mt * 16 + lr][kt * 32 + lg * 8];
            for (int kt = 0; kt < 2; ++kt)
                ah[kt] = *(const u16x8*)&h_s[hr][mt * 16 + lr][kt * 32 + lg * 8];
            f32x4 acc[4];
            for (int g = 0; g < 4; ++g) {
                f32x4 a = {bias_g[g], bias_g[g], bias_g[g], bias_g[g]};
                a = MFMA_BF16(ax[0], wg[g][0], a);
                a = MFMA_BF16(ax[1], wg[g][1], a);
                a = MFMA_BF16(ax[2], wg[g][2], a);
                a = MFMA_BF16(ax[3], wg[g][3], a);
                a = MFMA_BF16(ah[0], wg[g][4], a);
                a = MFMA_BF16(ah[1], wg[g][5], a);
                acc[g] = a;
            }
            for (int r = 0; r < 4; ++r) {
                float cn = sig_(acc[1][r]) * c_st[mt][r] + sig_(acc[0][r]) * tanh_(acc[2][r]);
                float hn = sig_(acc[3][r]) * tanh_(cn);
                c_st[mt][r] = cn;
                h_s[hw][mt * 16 + lg * 4 + r][w * 16 + lr] = f2b(hn);
            }
        }
        BARRIER_LDS();

        if (t >= 9) {
            // dec (out) + fused enc' (next rnn_in), both from h_s[hw] A-frags
            u16x8 ah2[2][2];
            for (int mt = 0; mt < 2; ++mt)
                for (int kt = 0; kt < 2; ++kt)
                    ah2[mt][kt] = *(const u16x8*)&h_s[hw][mt * 16 + lr][kt * 32 + lg * 8];
            const int nd = w * 16 + lr;
            if (t == 9) {
                if (w < 3 && nd < 34)
                    for (int mt = 0; mt < 2; ++mt)
                        for (int r = 0; r < 4; ++r)
                            prev[mt][r] = x[((b0 + mt * 16 + lg * 4 + r) * 60 + 9) * 34 + nd];
            } else if (w < 3) {
                for (int mt = 0; mt < 2; ++mt) {
                    f32x4 a = {bias_d, bias_d, bias_d, bias_d};
                    a = MFMA_BF16(ah2[mt][0], wd[0], a);
                    a = MFMA_BF16(ah2[mt][1], wd[1], a);
                    if (nd < 34)
                        for (int r = 0; r < 4; ++r) {
                            float o = a[r] + prev[mt][r];
                            prev[mt][r] = o;
                            out[((b0 + mt * 16 + lg * 4 + r) * 50 + (t - 10)) * 34 + nd] = o;
                        }
                }
            }
            if (t < 59) {
                for (int mt = 0; mt < 2; ++mt)
                    for (int ntl = 0; ntl < 2; ++ntl) {
                        f32x4 a = {bias_f[ntl], bias_f[ntl], bias_f[ntl], bias_f[ntl]};
                        a = MFMA_BF16(ah2[mt][0], wf[ntl][0], a);
                        a = MFMA_BF16(ah2[mt][1], wf[ntl][1], a);
                        for (int r = 0; r < 4; ++r)
                            x_s[mt * 16 + lg * 4 + r][(w * 2 + ntl) * 16 + lr] = f2b(fmaxf(a[r], 0.0f));
                    }
            }
            BARRIER_LDS();
        }
    }
}

extern "C" void kernel_launch(void* const* d_in, const int* in_sizes, int n_in,
                              void* d_out, int out_size, void* d_ws, size_t ws_size,
                              hipStream_t stream) {
    const float* x     = (const float*)d_in[0];
    const float* W_enc = (const float*)d_in[1];
    const float* b_enc = (const float*)d_in[2];
    const float* W_ih  = (const float*)d_in[3];
    const float* W_hh  = (const float*)d_in[4];
    const float* b_ih  = (const float*)d_in[5];
    const float* b_hh  = (const float*)d_in[6];
    const float* W_dec = (const float*)d_in[7];
    const float* b_dec = (const float*)d_in[8];
    float* out = (float*)d_out;
    // n_seeds (d_in[9]) is compile-time 10 for this problem shape.
    ar_lstm_kernel<<<512, 256, 0, stream>>>(x, W_enc, b_enc, W_ih, W_hh,
                                            b_ih, b_hh, W_dec, b_dec, out);
}